// Round 1
// 391.581 us; speedup vs baseline: 1.0794x; 1.0794x over previous
//
#include <hip/hip_runtime.h>

// Cost-volume builder:
// out[b, c2, d, h, w] with shape (4, 64, 48, 64, 128) fp32
//   c2 <  32: (w >= d) ? left [b, c2,    h, w    ] : 0
//   c2 >= 32: (w >= d) ? right[b, c2-32, h, w - d] : 0
//
// Write-bound: 402.7 MB out vs 8 MB in. The fill kernel on this box streams
// 6.25 TB/s; R3 (one 16B store per thread, 98K blocks) only reached ~2.4 TB/s
// because per-store overhead (wave setup, load latency, block churn) limited
// store issue rate.
//
// R4: loop inversion. One thread owns one float4 column (b,c2,h,w0) and walks
// all D=48 disparities: 48 nt-stores / 768 B per thread, grid = 2048 blocks
// (exactly one resident generation: 8 blocks/CU x 4 waves = 32 waves/CU).
//   - left:  load float4 once, store 48x with (w>=d) selects.
//   - right: sliding 2-register window; one new aligned float4 per 4
//     disparities, windows built by register shuffles. Feeding a=0 past the
//     row start reproduces the (w>=d) mask exactly -> no mask instructions.

#define BB 4
#define CC 32
#define HH 64
#define WW 128
#define DD 48

typedef float vfloat4 __attribute__((ext_vector_type(4)));

__global__ __launch_bounds__(256) void cost_kernel(
    const float* __restrict__ left,
    const float* __restrict__ right,
    float* __restrict__ out)
{
    // grid: (H*W/4/256 = 8, 1, B*2C = 256)
    const int p  = blockIdx.x * 256 + threadIdx.x;  // float4 index within (h,w) plane
    const int bc = blockIdx.z;                      // b*64 + c2
    const int b  = bc >> 6;
    const int c2 = bc & 63;
    const int h  = p >> 5;                          // W/4 = 32 float4 per row
    const int k0 = p & 31;                          // float4 column within row
    const int w0 = k0 * 4;                          // starting w of this float4

    const bool is_right = (c2 >= CC);               // uniform per block
    const int  c        = is_right ? (c2 - CC) : c2;
    const float* __restrict__ src = is_right ? right : left;
    const vfloat4* __restrict__ row4 =
        reinterpret_cast<const vfloat4*>(src + ((((size_t)b * CC + c) * HH + h) * WW));

    const int stride4 = HH * WW / 4;                // 2048 float4 per d-slab
    vfloat4* __restrict__ out4 = reinterpret_cast<vfloat4*>(out)
                               + (size_t)bc * DD * stride4 + p;

    if (!is_right) {
        // Load once, store D times. Only columns with w0 < DD ever mask.
        const vfloat4 lv = row4[k0];
        #pragma unroll
        for (int d = 0; d < DD; ++d) {
            vfloat4 o;
            o.x = (w0 + 0 >= d) ? lv.x : 0.0f;
            o.y = (w0 + 1 >= d) ? lv.y : 0.0f;
            o.z = (w0 + 2 >= d) ? lv.z : 0.0f;
            o.w = (w0 + 3 >= d) ? lv.w : 0.0f;
            __builtin_nontemporal_store(o, out4 + (size_t)d * stride4);
        }
    } else {
        // Sliding window: group g covers d = 4g..4g+3, reading
        // right[w0-d .. w0+3-d] from float4s b4 (=row4[k0-g]) and a4 (=row4[k0-g-1]).
        // a4 := 0 once the index drops below the row start — this IS the mask.
        vfloat4 b4 = row4[k0];
        int k = k0;
        #pragma unroll
        for (int g = 0; g < DD / 4; ++g) {
            vfloat4 a4 = (vfloat4)(0.0f);
            if (k >= 1) a4 = row4[k - 1];

            const vfloat4 o0 = b4;
            vfloat4 o1; o1.x = a4.w; o1.y = b4.x; o1.z = b4.y; o1.w = b4.z;
            vfloat4 o2; o2.x = a4.z; o2.y = a4.w; o2.z = b4.x; o2.w = b4.y;
            vfloat4 o3; o3.x = a4.y; o3.y = a4.z; o3.z = a4.w; o3.w = b4.x;

            __builtin_nontemporal_store(o0, out4 + (size_t)(4 * g + 0) * stride4);
            __builtin_nontemporal_store(o1, out4 + (size_t)(4 * g + 1) * stride4);
            __builtin_nontemporal_store(o2, out4 + (size_t)(4 * g + 2) * stride4);
            __builtin_nontemporal_store(o3, out4 + (size_t)(4 * g + 3) * stride4);

            b4 = a4;
            --k;
        }
    }
}

extern "C" void kernel_launch(void* const* d_in, const int* in_sizes, int n_in,
                              void* d_out, int out_size, void* d_ws, size_t ws_size,
                              hipStream_t stream)
{
    const float* left  = (const float*)d_in[0];
    const float* right = (const float*)d_in[1];
    float* out = (float*)d_out;

    dim3 grid(HH * WW / 4 / 256, 1, BB * 2 * CC);   // (8, 1, 256)
    cost_kernel<<<grid, dim3(256), 0, stream>>>(left, right, out);
}